// Round 19
// baseline (102.236 us; speedup 1.0000x reference)
//
#include <hip/hip_runtime.h>
#include <stdint.h>

// PointNet Feature Propagation, MI355X.  3 launches:
//  A  : fused  k1 three_nn (0..2047, exact f32 INSERT)
//             + k2_z = W2@p2 (2048..3071, 32s x 128o, W f32-direct)
//             + k2b y1=W1@p1 (3072..7167, 32n x 128o, W f32-direct)
//  K3a: y2 = y1 + sum_k w_k * ztb[idx_k]  (LDS-staged gather) + BN partials
//  K3c: y2 -> LDS transpose -> (stats from partials) BN+ReLU -> d_out f32

#define B_   16
#define N_   4096
#define S_   1024
#define D1_  64
#define D2_  256
#define OC_  256

typedef __attribute__((ext_vector_type(8))) short bf16x8;
typedef __attribute__((ext_vector_type(4))) float f32x4;
typedef __attribute__((ext_vector_type(4))) unsigned int u32x4;
typedef __attribute__((ext_vector_type(2))) unsigned int u32x2;

// workspace layout (bytes)
#define IDXW_OFF 0u           // 2 MB
#define ZTB_OFF  2097152u     // 8 MB
#define Y1_OFF   10485760u    // 32 MB
#define Y2_OFF   44040192u    // 32 MB
#define PART_OFF 77594624u    // 64 KB
#define WS_NEED  77826048u

__device__ __forceinline__ uint16_t f2bf(float f) {
    union { float f; uint32_t u; } v; v.f = f;
    uint32_t r = v.u + 0x7FFFu + ((v.u >> 16) & 1u);   // RNE
    return (uint16_t)(r >> 16);
}
__device__ __forceinline__ float bf2f(uint32_t h) {
    union { uint32_t u; float f; } v; v.u = h << 16;
    return v.f;
}
// 8 consecutive f32 -> bf16x8 (16B-aligned source)
__device__ __forceinline__ bf16x8 cvt8(const float* p) {
    f32x4 a = *(const f32x4*)p;
    f32x4 b = *(const f32x4*)(p + 4);
    union { uint32_t u[4]; bf16x8 v; } r;
    r.u[0] = (uint32_t)f2bf(a.x) | ((uint32_t)f2bf(a.y) << 16);
    r.u[1] = (uint32_t)f2bf(a.z) | ((uint32_t)f2bf(a.w) << 16);
    r.u[2] = (uint32_t)f2bf(b.x) | ((uint32_t)f2bf(b.y) << 16);
    r.u[3] = (uint32_t)f2bf(b.z) | ((uint32_t)f2bf(b.w) << 16);
    return r.v;
}

#define INSERT(d, sidx, d0, d1, d2, i0, i1, i2) do {                      \
    bool ca = (d) < (d2); bool cb = (d) < (d1); bool cc = (d) < (d0);     \
    float _n1 = __builtin_amdgcn_fmed3f((d), (d0), (d1));                 \
    float _n2 = __builtin_amdgcn_fmed3f((d), (d1), (d2));                 \
    int _j2 = cb ? (i1) : (ca ? (sidx) : (i2));                          \
    int _j1 = cc ? (i0) : (cb ? (sidx) : (i1));                          \
    i0 = cc ? (sidx) : (i0);                                              \
    d0 = fminf((d), (d0)); d1 = _n1; d2 = _n2; i1 = _j1; i2 = _j2;        \
} while (0)

// ---------------- A: k1 (0..2047) + k2_z (2048..3071) + k2b (3072..7167) ----------------
__global__ void __launch_bounds__(256, 8)
kA(const float* __restrict__ xyz1, const float* __restrict__ xyz2,
   int* __restrict__ idxw, const float* __restrict__ p1,
   const float* __restrict__ p2, const float* __restrict__ W,
   uint16_t* __restrict__ ztb, uint16_t* __restrict__ y1) {
    __shared__ char smem[16512];
    int i = blockIdx.x;
    int t = threadIdx.x, l = t & 63, w = t >> 6;
    if (i < 2048) {
        // ---- k1: three_nn, 32 n/block, 8 s-chunks of 128, exact f32 INSERT ----
        int b  = i >> 7;
        int n0 = (i & 127) * 32;
        float4* pts = (float4*)smem;    // [8 chunks][129]

        for (int s = t; s < S_; s += 256) {
            const float* p = xyz2 + ((size_t)b * S_ + s) * 3;
            float sx = p[0], sy = p[1], sz = p[2];
            float s2 = fmaf(sz, sz, fmaf(sy, sy, sx * sx));
            pts[(s >> 7) * 129 + (s & 127)] = make_float4(sx, sy, sz, s2);
        }
        __syncthreads();

        int chunk = t & 7, nidx = t >> 3;
        int n = n0 + nidx;
        const float* q = xyz1 + ((size_t)b * N_ + n) * 3;
        float ax = q[0], ay = q[1], az = q[2];
        float m2x = -2.0f * ax, m2y = -2.0f * ay, m2z = -2.0f * az;
        float q2 = fmaf(az, az, fmaf(ay, ay, ax * ax));

        float d0 = 3.4e38f, d1 = 3.4e38f, d2 = 3.4e38f;
        int   i0 = 0, i1 = 0, i2 = 0;

        const float4* base = pts + chunk * 129;
        int sbase = chunk * 128;
        #pragma unroll 4
        for (int j = 0; j < 128; j++) {
            float4 qq = base[j];
            int s = sbase + j;
            float d = fmaf(qq.x, m2x, fmaf(qq.y, m2y, fmaf(qq.z, m2z, qq.w)));
            INSERT(d, s, d0, d1, d2, i0, i1, i2);
        }
        #pragma unroll
        for (int m = 1; m <= 4; m <<= 1) {
            float e0 = __shfl_xor(d0, m), e1 = __shfl_xor(d1, m), e2 = __shfl_xor(d2, m);
            int   g0 = __shfl_xor(i0, m), g1 = __shfl_xor(i1, m), g2 = __shfl_xor(i2, m);
            INSERT(e0, g0, d0, d1, d2, i0, i1, i2);
            INSERT(e1, g1, d0, d1, d2, i0, i1, i2);
            INSERT(e2, g2, d0, d1, d2, i0, i1, i2);
        }
        if (chunk == 0) {
            float dd0 = d0 + q2, dd1 = d1 + q2, dd2 = d2 + q2;
            float r0 = 1.0f / (dd0 + 1e-8f), r1 = 1.0f / (dd1 + 1e-8f), r2 = 1.0f / (dd2 + 1e-8f);
            float rs = r0 + r1 + r2;
            float* fw = (float*)idxw;
            int bb = (b * N_ + n) * 8;
            idxw[bb + 0] = i0; idxw[bb + 1] = i1; idxw[bb + 2] = i2;
            fw[bb + 4] = r0 / rs; fw[bb + 5] = r1 / rs; fw[bb + 6] = r2 / rs;
        }
    } else if (i < 3072) {
        // ---- k2_z: ztb = W2@p2; 32s x 128o per block; W2 f32-direct ----
        int i2 = i - 2048;
        uint16_t* a_t = (uint16_t*)smem;   // [32 s][256 c] bf16, 512B rows, swz <<4
        int b = i2 >> 6, s0 = ((i2 >> 1) & 31) * 32, oh = i2 & 1;
        int sA = t & 31, cpg = t >> 5;
        const float* p2b = p2 + (size_t)b * D2_ * S_ + s0;
        #pragma unroll
        for (int j = 0; j < 16; j++) {
            int cp = cpg + 8 * j;
            float lo = p2b[(size_t)(2 * cp) * S_ + sA];
            float hi = p2b[(size_t)(2 * cp + 1) * S_ + sA];
            uint32_t pk = (uint32_t)f2bf(lo) | ((uint32_t)f2bf(hi) << 16);
            *(uint32_t*)((char*)a_t + sA * 512 + ((cp * 4) ^ ((sA & 7) << 4))) = pk;
        }
        __syncthreads();
        f32x4 acc[2][2] = {};   // [mi(s16)][oj(o16)]
        int ls = l & 15, swzs = (ls & 7) << 4;
        #pragma unroll
        for (int ks = 0; ks < 8; ks++) {
            int co = ks * 32 + (l >> 4) * 8;
            bf16x8 a0 = *(const bf16x8*)((const char*)a_t + ls * 512 + ((co * 2) ^ swzs));
            bf16x8 a1 = *(const bf16x8*)((const char*)a_t + (16 + ls) * 512 + ((co * 2) ^ swzs));
            bf16x8 bbf[2];
            #pragma unroll
            for (int oj = 0; oj < 2; oj++) {
                int o = oh * 128 + w * 32 + oj * 16 + ls;
                bbf[oj] = cvt8(W + (size_t)o * 320 + 64 + co);
            }
            #pragma unroll
            for (int oj = 0; oj < 2; oj++) {
                acc[0][oj] = __builtin_amdgcn_mfma_f32_16x16x32_bf16(a0, bbf[oj], acc[0][oj], 0, 0, 0);
                acc[1][oj] = __builtin_amdgcn_mfma_f32_16x16x32_bf16(a1, bbf[oj], acc[1][oj], 0, 0, 0);
            }
        }
        #pragma unroll
        for (int mi = 0; mi < 2; mi++)
            #pragma unroll
            for (int oj = 0; oj < 2; oj++) {
                int og = oh * 8 + w * 2 + oj;
                uint16_t* zb = ztb + ((size_t)(b * 16 + og) * S_ + s0 + mi * 16 + (l >> 4) * 4) * 16 + ls;
                #pragma unroll
                for (int r = 0; r < 4; r++)
                    zb[(size_t)r * 16] = f2bf(acc[mi][oj][r]);
            }
    } else {
        // ---- k2b: y1 = W1@p1; 32n x 128o per block; W1 f32-direct ----
        int j2 = i - 3072;
        int b = j2 >> 8, n0 = ((j2 >> 1) & 127) * 32, oh = j2 & 1;
        uint16_t* pt = (uint16_t*)smem;   // [32 n][64 c], 128B rows, swz <<4
        {
            int nn = t & 31;
            const float* p1b = p1 + (size_t)b * D1_ * N_ + n0;
            #pragma unroll
            for (int j = 0; j < 4; j++) {
                int cp = (t >> 5) + 8 * j;
                float lo = p1b[(size_t)(2 * cp) * N_ + nn];
                float hi = p1b[(size_t)(2 * cp + 1) * N_ + nn];
                uint32_t pk = (uint32_t)f2bf(lo) | ((uint32_t)f2bf(hi) << 16);
                *(uint32_t*)((char*)pt + nn * 128 + ((cp * 4) ^ ((nn & 7) << 4))) = pk;
            }
        }
        bf16x8 af[2][2];
        #pragma unroll
        for (int ks = 0; ks < 2; ks++)
            #pragma unroll
            for (int mi = 0; mi < 2; mi++) {
                int o = oh * 128 + w * 32 + mi * 16 + (l & 15);
                af[ks][mi] = cvt8(W + (size_t)o * 320 + ks * 32 + (l >> 4) * 8);
            }
        f32x4 acc[2][2] = {};   // [mi(o)][bj(n)]
        __syncthreads();
        #pragma unroll
        for (int ks = 0; ks < 2; ks++) {
            bf16x8 bf[2];
            int co = ks * 32 + (l >> 4) * 8;
            #pragma unroll
            for (int bj = 0; bj < 2; bj++) {
                int nn = bj * 16 + (l & 15);
                bf[bj] = *(const bf16x8*)((const char*)pt + nn * 128 + ((co * 2) ^ ((nn & 7) << 4)));
            }
            #pragma unroll
            for (int mi = 0; mi < 2; mi++)
                #pragma unroll
                for (int bj = 0; bj < 2; bj++)
                    acc[mi][bj] = __builtin_amdgcn_mfma_f32_16x16x32_bf16(
                        af[ks][mi], bf[bj], acc[mi][bj], 0, 0, 0);
        }
        #pragma unroll
        for (int mi = 0; mi < 2; mi++) {
            int og = oh * 8 + w * 2 + mi;
            uint16_t* yb = y1 + ((size_t)(b * 16 + og)) * N_ * 16;
            #pragma unroll
            for (int bj = 0; bj < 2; bj++) {
                int n = n0 + bj * 16 + (l & 15);
                int oo = (l >> 4) * 4;
                u32x2 v;
                v.x = (uint32_t)f2bf(acc[mi][bj][0]) | ((uint32_t)f2bf(acc[mi][bj][1]) << 16);
                v.y = (uint32_t)f2bf(acc[mi][bj][2]) | ((uint32_t)f2bf(acc[mi][bj][3]) << 16);
                __builtin_nontemporal_store(v, (u32x2*)(yb + (size_t)n * 16 + oo));
            }
        }
    }
}

// ---------------- K3a: LDS-staged gather -> y2 bf16 + BN partials ----------------
__global__ void __launch_bounds__(1024, 8)
k3a(const uint16_t* __restrict__ y1, const uint16_t* __restrict__ ztb,
    const int* __restrict__ idxw, uint16_t* __restrict__ y2,
    float* __restrict__ partials) {
    __shared__ char zsm[49152];          // [1024 s][48B] rows (32B used)
    __shared__ float red[16][16][2];
    int bi = blockIdx.x;                 // 512: b*32 + og*2 + nh
    int b = bi >> 5, og = (bi >> 1) & 15, nh = bi & 1;
    int u = threadIdx.x, l = u & 63, w = u >> 6;   // 16 waves
    {
        const u32x4* src = (const u32x4*)(ztb + ((size_t)(b * 16 + og)) * S_ * 16);
        #pragma unroll
        for (int k = 0; k < 2; k++) {
            int g = k * 1024 + u;
            u32x4 v = src[g];
            *(u32x4*)(zsm + (g >> 1) * 48 + (g & 1) * 16) = v;
        }
    }
    __syncthreads();
    int q = l >> 2, sub = l & 3;
    float s1l[4] = {0.f, 0.f, 0.f, 0.f}, s2l[4] = {0.f, 0.f, 0.f, 0.f};
    int nbase = nh * 2048 + w * 128;
    const uint16_t* y1b = y1 + ((size_t)(b * 16 + og)) * N_ * 16;
    uint16_t* y2b = y2 + ((size_t)(b * 16 + og)) * N_ * 16;
    #pragma unroll 2
    for (int it = 0; it < 8; it++) {
        int n = nbase + it * 16 + q;
        u32x2 y1v = __builtin_nontemporal_load((const u32x2*)(y1b + (size_t)n * 16 + sub * 4));
        const int* ib = idxw + ((size_t)(b * N_ + n)) * 8;
        int4   iv = *(const int4*)ib;
        float4 wv = *((const float4*)ib + 1);
        u32x2 z0 = *(const u32x2*)(zsm + iv.x * 48 + sub * 8);
        u32x2 z1 = *(const u32x2*)(zsm + iv.y * 48 + sub * 8);
        u32x2 z2 = *(const u32x2*)(zsm + iv.z * 48 + sub * 8);
        float a0 = bf2f(y1v.x & 0xffff) + wv.x * bf2f(z0.x & 0xffff) + wv.y * bf2f(z1.x & 0xffff) + wv.z * bf2f(z2.x & 0xffff);
        float a1 = bf2f(y1v.x >> 16)    + wv.x * bf2f(z0.x >> 16)    + wv.y * bf2f(z1.x >> 16)    + wv.z * bf2f(z2.x >> 16);
        float a2 = bf2f(y1v.y & 0xffff) + wv.x * bf2f(z0.y & 0xffff) + wv.y * bf2f(z1.y & 0xffff) + wv.z * bf2f(z2.y & 0xffff);
        float a3 = bf2f(y1v.y >> 16)    + wv.x * bf2f(z0.y >> 16)    + wv.y * bf2f(z1.y >> 16)    + wv.z * bf2f(z2.y >> 16);
        s1l[0] += a0; s2l[0] += a0 * a0;
        s1l[1] += a1; s2l[1] += a1 * a1;
        s1l[2] += a2; s2l[2] += a2 * a2;
        s1l[3] += a3; s2l[3] += a3 * a3;
        u32x2 vv;
        vv.x = (uint32_t)f2bf(a0) | ((uint32_t)f2bf(a1) << 16);
        vv.y = (uint32_t)f2bf(a2) | ((uint32_t)f2bf(a3) << 16);
        __builtin_nontemporal_store(vv, (u32x2*)(y2b + (size_t)n * 16 + sub * 4));
    }
    #pragma unroll
    for (int m = 4; m <= 32; m <<= 1)
        #pragma unroll
        for (int j = 0; j < 4; j++) {
            s1l[j] += __shfl_xor(s1l[j], m);
            s2l[j] += __shfl_xor(s2l[j], m);
        }
    if (l < 4) {
        #pragma unroll
        for (int j = 0; j < 4; j++) {
            red[w][sub * 4 + j][0] = s1l[j];
            red[w][sub * 4 + j][1] = s2l[j];
        }
    }
    __syncthreads();
    if (u < 32) {
        int oi = u >> 1, st = u & 1;
        float s = 0.f;
        #pragma unroll
        for (int ww = 0; ww < 16; ww++) s += red[ww][oi][st];
        partials[(size_t)bi * 32 + oi * 2 + st] = s;
    }
}

// ---------------- K3c: stats + y2 -> LDS transpose -> BN+ReLU -> out ----------------
__global__ void __launch_bounds__(256, 8)
k3c(const uint16_t* __restrict__ y2, const float* __restrict__ partials,
    const float* __restrict__ gamma, const float* __restrict__ beta,
    float* __restrict__ out) {
    __shared__ uint16_t ty[16 * 256];   // [16 o][256 n] bf16, byte XOR bit4 by (o&7)
    __shared__ float stat[32];
    __shared__ float sbsh[32];
    int bi = blockIdx.x;                // 4096: b*256 + og*16 + nc
    int b = bi >> 8, og = (bi >> 4) & 15, nc = bi & 15;
    int u = threadIdx.x;
    const uint16_t* src = y2 + (((size_t)(b * 16 + og)) * N_ + nc * 256) * 16;
    u32x4 va = __builtin_nontemporal_load((const u32x4*)(src + (size_t)u * 16));
    u32x4 vb = __builtin_nontemporal_load((const u32x4*)(src + (size_t)u * 16 + 8));
    if (u < 32) {
        int oi = u >> 1, st = u & 1;
        float s = 0.f;
        #pragma unroll 4
        for (int t2 = 0; t2 < 32; t2++) {
            int row = (t2 >> 1) * 32 + og * 2 + (t2 & 1);
            s += partials[(size_t)row * 32 + oi * 2 + st];
        }
        stat[u] = s;
    }
    __syncthreads();
    if (u < 16) {
        float mean = stat[u * 2] / 65536.0f;
        float var  = stat[u * 2 + 1] / 65536.0f - mean * mean;
        int o_g = og * 16 + u;
        float scale = gamma[o_g] * rsqrtf(var + 1e-5f);
        sbsh[u * 2]     = scale;
        sbsh[u * 2 + 1] = beta[o_g] - mean * scale;
    }
    uint32_t words[8] = {va.x, va.y, va.z, va.w, vb.x, vb.y, vb.z, vb.w};
    #pragma unroll
    for (int h = 0; h < 8; h++) {
        int o0 = h * 2, o1 = h * 2 + 1;
        *(uint16_t*)((char*)ty + o0 * 512 + ((u * 2) ^ ((o0 & 7) << 4))) = (uint16_t)(words[h] & 0xffff);
        *(uint16_t*)((char*)ty + o1 * 512 + ((u * 2) ^ ((o1 & 7) << 4))) = (uint16_t)(words[h] >> 16);
    }
    __syncthreads();
    int o = u >> 4, k = u & 15;
    int x = (o & 7) << 4;
    int o_g = og * 16 + o;
    float scale = sbsh[o * 2], bias = sbsh[o * 2 + 1];
    float* dst = out + ((size_t)(b * OC_ + o_g)) * N_ + nc * 256;
    #pragma unroll
    for (int g2 = 0; g2 < 4; g2++) {
        uint64_t z = *(const uint64_t*)((const char*)ty + o * 512 + ((g2 * 128 + k * 8) ^ x));
        f32x4 r;
        r.x = fmaxf(0.f, fmaf(bf2f((uint32_t)(z       ) & 0xffff), scale, bias));
        r.y = fmaxf(0.f, fmaf(bf2f((uint32_t)(z >> 16 ) & 0xffff), scale, bias));
        r.z = fmaxf(0.f, fmaf(bf2f((uint32_t)(z >> 32 ) & 0xffff), scale, bias));
        r.w = fmaxf(0.f, fmaf(bf2f((uint32_t)(z >> 48 ) & 0xffff), scale, bias));
        __builtin_nontemporal_store(r, (f32x4*)(dst + g2 * 64 + k * 4));
    }
}

extern "C" void kernel_launch(void* const* d_in, const int* in_sizes, int n_in,
                              void* d_out, int out_size, void* d_ws, size_t ws_size,
                              hipStream_t stream) {
    const float* xyz1  = (const float*)d_in[0];
    const float* xyz2  = (const float*)d_in[1];
    const float* p1    = (const float*)d_in[2];
    const float* p2    = (const float*)d_in[3];
    const float* W     = (const float*)d_in[4];
    const float* gamma = (const float*)d_in[5];
    const float* beta  = (const float*)d_in[6];
    float* out = (float*)d_out;
    char* ws = (char*)d_ws;
    if (ws_size < (size_t)WS_NEED) return;

    int*      idxw     = (int*)(ws + IDXW_OFF);
    uint16_t* ztb      = (uint16_t*)(ws + ZTB_OFF);
    uint16_t* y1       = (uint16_t*)(ws + Y1_OFF);
    uint16_t* y2       = (uint16_t*)(ws + Y2_OFF);
    float*    partials = (float*)(ws + PART_OFF);

    hipLaunchKernelGGL(kA,  dim3(7168), dim3(256),  0, stream,
                       xyz1, xyz2, idxw, p1, p2, W, ztb, y1);
    hipLaunchKernelGGL(k3a, dim3(512),  dim3(1024), 0, stream,
                       y1, ztb, idxw, y2, partials);
    hipLaunchKernelGGL(k3c, dim3(4096), dim3(256),  0, stream,
                       y2, partials, gamma, beta, out);
}

// Round 20
// 93.690 us; speedup vs baseline: 1.0912x; 1.0912x over previous
//
#include <hip/hip_runtime.h>
#include <stdint.h>

// PointNet Feature Propagation, MI355X.  4 launches (best validated config, R15):
//  K0 : W f32 -> w1b bf16 [256][64], w2b bf16 [256][256]   (tiny)
//  A  : fused  k1 three_nn (0..2047, exact f32 INSERT)
//             + k2_z = W2@p2 (2048..3071, 32s x 128o)
//             + k2b y1=W1@p1 (3072..7167, 32n x 128o)
//  K3a: y2 = y1 + sum_k w_k * ztb[idx_k]  (LDS-staged gather) + BN partials
//  K3c: y2 -> LDS transpose -> (stats from partials) BN+ReLU -> d_out f32

#define B_   16
#define N_   4096
#define S_   1024
#define D1_  64
#define D2_  256
#define OC_  256

typedef __attribute__((ext_vector_type(8))) short bf16x8;
typedef __attribute__((ext_vector_type(4))) float f32x4;
typedef __attribute__((ext_vector_type(4))) unsigned int u32x4;
typedef __attribute__((ext_vector_type(2))) unsigned int u32x2;

// workspace layout (bytes)
#define IDXW_OFF 0u           // 2 MB
#define ZTB_OFF  2097152u     // 8 MB
#define Y1_OFF   10485760u    // 32 MB
#define Y2_OFF   44040192u    // 32 MB
#define PART_OFF 77594624u    // 64 KB
#define W1B_OFF  77662208u    // 32 KB
#define W2B_OFF  77694976u    // 128 KB
#define WS_NEED  77826048u

__device__ __forceinline__ uint16_t f2bf(float f) {
    union { float f; uint32_t u; } v; v.f = f;
    uint32_t r = v.u + 0x7FFFu + ((v.u >> 16) & 1u);   // RNE
    return (uint16_t)(r >> 16);
}
__device__ __forceinline__ float bf2f(uint32_t h) {
    union { uint32_t u; float f; } v; v.u = h << 16;
    return v.f;
}

#define INSERT(d, sidx, d0, d1, d2, i0, i1, i2) do {                      \
    bool ca = (d) < (d2); bool cb = (d) < (d1); bool cc = (d) < (d0);     \
    float _n1 = __builtin_amdgcn_fmed3f((d), (d0), (d1));                 \
    float _n2 = __builtin_amdgcn_fmed3f((d), (d1), (d2));                 \
    int _j2 = cb ? (i1) : (ca ? (sidx) : (i2));                          \
    int _j1 = cc ? (i0) : (cb ? (sidx) : (i1));                          \
    i0 = cc ? (sidx) : (i0);                                              \
    d0 = fminf((d), (d0)); d1 = _n1; d2 = _n2; i1 = _j1; i2 = _j2;        \
} while (0)

// ---------------- K0: weight conversion ----------------
__global__ void k0_prep(const float* __restrict__ W,
                        uint16_t* __restrict__ w1b, uint16_t* __restrict__ w2b) {
    int e = blockIdx.x * 256 + threadIdx.x;
    if (e >= OC_ * 320) return;
    int o = e / 320, c = e % 320;
    uint16_t b = f2bf(W[e]);
    if (c < 64) w1b[o * 64 + c] = b;
    else        w2b[o * 256 + (c - 64)] = b;
}

// ---------------- A: k1 (0..2047) + k2_z (2048..3071) + k2b (3072..7167) ----------------
__global__ void __launch_bounds__(256, 8)
kA(const float* __restrict__ xyz1, const float* __restrict__ xyz2,
   int* __restrict__ idxw, const float* __restrict__ p1,
   const float* __restrict__ p2, const uint16_t* __restrict__ w1b,
   const uint16_t* __restrict__ w2b, uint16_t* __restrict__ ztb,
   uint16_t* __restrict__ y1) {
    __shared__ char smem[16512];
    int i = blockIdx.x;
    int t = threadIdx.x, l = t & 63, w = t >> 6;
    if (i < 2048) {
        // ---- k1: three_nn, 32 n/block, 8 s-chunks of 128, exact f32 INSERT ----
        int b  = i >> 7;
        int n0 = (i & 127) * 32;
        float4* pts = (float4*)smem;    // [8 chunks][129]

        for (int s = t; s < S_; s += 256) {
            const float* p = xyz2 + ((size_t)b * S_ + s) * 3;
            float sx = p[0], sy = p[1], sz = p[2];
            float s2 = fmaf(sz, sz, fmaf(sy, sy, sx * sx));
            pts[(s >> 7) * 129 + (s & 127)] = make_float4(sx, sy, sz, s2);
        }
        __syncthreads();

        int chunk = t & 7, nidx = t >> 3;
        int n = n0 + nidx;
        const float* q = xyz1 + ((size_t)b * N_ + n) * 3;
        float ax = q[0], ay = q[1], az = q[2];
        float m2x = -2.0f * ax, m2y = -2.0f * ay, m2z = -2.0f * az;
        float q2 = fmaf(az, az, fmaf(ay, ay, ax * ax));

        float d0 = 3.4e38f, d1 = 3.4e38f, d2 = 3.4e38f;
        int   i0 = 0, i1 = 0, i2 = 0;

        const float4* base = pts + chunk * 129;
        int sbase = chunk * 128;
        #pragma unroll 4
        for (int j = 0; j < 128; j++) {
            float4 qq = base[j];
            int s = sbase + j;
            float d = fmaf(qq.x, m2x, fmaf(qq.y, m2y, fmaf(qq.z, m2z, qq.w)));
            INSERT(d, s, d0, d1, d2, i0, i1, i2);
        }
        #pragma unroll
        for (int m = 1; m <= 4; m <<= 1) {
            float e0 = __shfl_xor(d0, m), e1 = __shfl_xor(d1, m), e2 = __shfl_xor(d2, m);
            int   g0 = __shfl_xor(i0, m), g1 = __shfl_xor(i1, m), g2 = __shfl_xor(i2, m);
            INSERT(e0, g0, d0, d1, d2, i0, i1, i2);
            INSERT(e1, g1, d0, d1, d2, i0, i1, i2);
            INSERT(e2, g2, d0, d1, d2, i0, i1, i2);
        }
        if (chunk == 0) {
            float dd0 = d0 + q2, dd1 = d1 + q2, dd2 = d2 + q2;
            float r0 = 1.0f / (dd0 + 1e-8f), r1 = 1.0f / (dd1 + 1e-8f), r2 = 1.0f / (dd2 + 1e-8f);
            float rs = r0 + r1 + r2;
            float* fw = (float*)idxw;
            int bb = (b * N_ + n) * 8;
            idxw[bb + 0] = i0; idxw[bb + 1] = i1; idxw[bb + 2] = i2;
            fw[bb + 4] = r0 / rs; fw[bb + 5] = r1 / rs; fw[bb + 6] = r2 / rs;
        }
    } else if (i < 3072) {
        // ---- k2_z: ztb = W2@p2; 32s x 128o per block ----
        int i2 = i - 2048;
        uint16_t* a_t = (uint16_t*)smem;   // [32 s][256 c] bf16, 512B rows, swz <<4
        int b = i2 >> 6, s0 = ((i2 >> 1) & 31) * 32, oh = i2 & 1;
        int sA = t & 31, cpg = t >> 5;
        const float* p2b = p2 + (size_t)b * D2_ * S_ + s0;
        #pragma unroll
        for (int j = 0; j < 16; j++) {
            int cp = cpg + 8 * j;
            float lo = p2b[(size_t)(2 * cp) * S_ + sA];
            float hi = p2b[(size_t)(2 * cp + 1) * S_ + sA];
            uint32_t pk = (uint32_t)f2bf(lo) | ((uint32_t)f2bf(hi) << 16);
            *(uint32_t*)((char*)a_t + sA * 512 + ((cp * 4) ^ ((sA & 7) << 4))) = pk;
        }
        __syncthreads();
        f32x4 acc[2][2] = {};   // [mi(s16)][oj(o16)]
        int ls = l & 15, swzs = (ls & 7) << 4;
        #pragma unroll
        for (int ks = 0; ks < 8; ks++) {
            int co = ks * 32 + (l >> 4) * 8;
            bf16x8 a0 = *(const bf16x8*)((const char*)a_t + ls * 512 + ((co * 2) ^ swzs));
            bf16x8 a1 = *(const bf16x8*)((const char*)a_t + (16 + ls) * 512 + ((co * 2) ^ swzs));
            bf16x8 bbf[2];
            #pragma unroll
            for (int oj = 0; oj < 2; oj++) {
                int o = oh * 128 + w * 32 + oj * 16 + ls;
                bbf[oj] = *(const bf16x8*)(w2b + (size_t)o * 256 + co);
            }
            #pragma unroll
            for (int oj = 0; oj < 2; oj++) {
                acc[0][oj] = __builtin_amdgcn_mfma_f32_16x16x32_bf16(a0, bbf[oj], acc[0][oj], 0, 0, 0);
                acc[1][oj] = __builtin_amdgcn_mfma_f32_16x16x32_bf16(a1, bbf[oj], acc[1][oj], 0, 0, 0);
            }
        }
        #pragma unroll
        for (int mi = 0; mi < 2; mi++)
            #pragma unroll
            for (int oj = 0; oj < 2; oj++) {
                int og = oh * 8 + w * 2 + oj;
                uint16_t* zb = ztb + ((size_t)(b * 16 + og) * S_ + s0 + mi * 16 + (l >> 4) * 4) * 16 + ls;
                #pragma unroll
                for (int r = 0; r < 4; r++)
                    zb[(size_t)r * 16] = f2bf(acc[mi][oj][r]);
            }
    } else {
        // ---- k2b: y1 = W1@p1; 32n x 128o per block ----
        int j2 = i - 3072;
        int b = j2 >> 8, n0 = ((j2 >> 1) & 127) * 32, oh = j2 & 1;
        uint16_t* pt = (uint16_t*)smem;   // [32 n][64 c], 128B rows, swz <<4
        {
            int nn = t & 31;
            const float* p1b = p1 + (size_t)b * D1_ * N_ + n0;
            #pragma unroll
            for (int j = 0; j < 4; j++) {
                int cp = (t >> 5) + 8 * j;
                float lo = p1b[(size_t)(2 * cp) * N_ + nn];
                float hi = p1b[(size_t)(2 * cp + 1) * N_ + nn];
                uint32_t pk = (uint32_t)f2bf(lo) | ((uint32_t)f2bf(hi) << 16);
                *(uint32_t*)((char*)pt + nn * 128 + ((cp * 4) ^ ((nn & 7) << 4))) = pk;
            }
        }
        bf16x8 af[2][2];
        #pragma unroll
        for (int ks = 0; ks < 2; ks++)
            #pragma unroll
            for (int mi = 0; mi < 2; mi++) {
                int o = oh * 128 + w * 32 + mi * 16 + (l & 15);
                af[ks][mi] = *(const bf16x8*)(w1b + (size_t)o * 64 + ks * 32 + (l >> 4) * 8);
            }
        f32x4 acc[2][2] = {};   // [mi(o)][bj(n)]
        __syncthreads();
        #pragma unroll
        for (int ks = 0; ks < 2; ks++) {
            bf16x8 bf[2];
            int co = ks * 32 + (l >> 4) * 8;
            #pragma unroll
            for (int bj = 0; bj < 2; bj++) {
                int nn = bj * 16 + (l & 15);
                bf[bj] = *(const bf16x8*)((const char*)pt + nn * 128 + ((co * 2) ^ ((nn & 7) << 4)));
            }
            #pragma unroll
            for (int mi = 0; mi < 2; mi++)
                #pragma unroll
                for (int bj = 0; bj < 2; bj++)
                    acc[mi][bj] = __builtin_amdgcn_mfma_f32_16x16x32_bf16(
                        af[ks][mi], bf[bj], acc[mi][bj], 0, 0, 0);
        }
        #pragma unroll
        for (int mi = 0; mi < 2; mi++) {
            int og = oh * 8 + w * 2 + mi;
            uint16_t* yb = y1 + ((size_t)(b * 16 + og)) * N_ * 16;
            #pragma unroll
            for (int bj = 0; bj < 2; bj++) {
                int n = n0 + bj * 16 + (l & 15);
                int oo = (l >> 4) * 4;
                u32x2 v;
                v.x = (uint32_t)f2bf(acc[mi][bj][0]) | ((uint32_t)f2bf(acc[mi][bj][1]) << 16);
                v.y = (uint32_t)f2bf(acc[mi][bj][2]) | ((uint32_t)f2bf(acc[mi][bj][3]) << 16);
                __builtin_nontemporal_store(v, (u32x2*)(yb + (size_t)n * 16 + oo));
            }
        }
    }
}

// ---------------- K3a: LDS-staged gather -> y2 bf16 + BN partials ----------------
__global__ void __launch_bounds__(1024, 8)
k3a(const uint16_t* __restrict__ y1, const uint16_t* __restrict__ ztb,
    const int* __restrict__ idxw, uint16_t* __restrict__ y2,
    float* __restrict__ partials) {
    __shared__ char zsm[49152];          // [1024 s][48B] rows (32B used)
    __shared__ float red[16][16][2];
    int bi = blockIdx.x;                 // 512: b*32 + og*2 + nh
    int b = bi >> 5, og = (bi >> 1) & 15, nh = bi & 1;
    int u = threadIdx.x, l = u & 63, w = u >> 6;   // 16 waves
    {
        const u32x4* src = (const u32x4*)(ztb + ((size_t)(b * 16 + og)) * S_ * 16);
        #pragma unroll
        for (int k = 0; k < 2; k++) {
            int g = k * 1024 + u;
            u32x4 v = src[g];
            *(u32x4*)(zsm + (g >> 1) * 48 + (g & 1) * 16) = v;
        }
    }
    __syncthreads();
    int q = l >> 2, sub = l & 3;
    float s1l[4] = {0.f, 0.f, 0.f, 0.f}, s2l[4] = {0.f, 0.f, 0.f, 0.f};
    int nbase = nh * 2048 + w * 128;
    const uint16_t* y1b = y1 + ((size_t)(b * 16 + og)) * N_ * 16;
    uint16_t* y2b = y2 + ((size_t)(b * 16 + og)) * N_ * 16;
    #pragma unroll 2
    for (int it = 0; it < 8; it++) {
        int n = nbase + it * 16 + q;
        u32x2 y1v = __builtin_nontemporal_load((const u32x2*)(y1b + (size_t)n * 16 + sub * 4));
        const int* ib = idxw + ((size_t)(b * N_ + n)) * 8;
        int4   iv = *(const int4*)ib;
        float4 wv = *((const float4*)ib + 1);
        u32x2 z0 = *(const u32x2*)(zsm + iv.x * 48 + sub * 8);
        u32x2 z1 = *(const u32x2*)(zsm + iv.y * 48 + sub * 8);
        u32x2 z2 = *(const u32x2*)(zsm + iv.z * 48 + sub * 8);
        float a0 = bf2f(y1v.x & 0xffff) + wv.x * bf2f(z0.x & 0xffff) + wv.y * bf2f(z1.x & 0xffff) + wv.z * bf2f(z2.x & 0xffff);
        float a1 = bf2f(y1v.x >> 16)    + wv.x * bf2f(z0.x >> 16)    + wv.y * bf2f(z1.x >> 16)    + wv.z * bf2f(z2.x >> 16);
        float a2 = bf2f(y1v.y & 0xffff) + wv.x * bf2f(z0.y & 0xffff) + wv.y * bf2f(z1.y & 0xffff) + wv.z * bf2f(z2.y & 0xffff);
        float a3 = bf2f(y1v.y >> 16)    + wv.x * bf2f(z0.y >> 16)    + wv.y * bf2f(z1.y >> 16)    + wv.z * bf2f(z2.y >> 16);
        s1l[0] += a0; s2l[0] += a0 * a0;
        s1l[1] += a1; s2l[1] += a1 * a1;
        s1l[2] += a2; s2l[2] += a2 * a2;
        s1l[3] += a3; s2l[3] += a3 * a3;
        u32x2 vv;
        vv.x = (uint32_t)f2bf(a0) | ((uint32_t)f2bf(a1) << 16);
        vv.y = (uint32_t)f2bf(a2) | ((uint32_t)f2bf(a3) << 16);
        __builtin_nontemporal_store(vv, (u32x2*)(y2b + (size_t)n * 16 + sub * 4));
    }
    #pragma unroll
    for (int m = 4; m <= 32; m <<= 1)
        #pragma unroll
        for (int j = 0; j < 4; j++) {
            s1l[j] += __shfl_xor(s1l[j], m);
            s2l[j] += __shfl_xor(s2l[j], m);
        }
    if (l < 4) {
        #pragma unroll
        for (int j = 0; j < 4; j++) {
            red[w][sub * 4 + j][0] = s1l[j];
            red[w][sub * 4 + j][1] = s2l[j];
        }
    }
    __syncthreads();
    if (u < 32) {
        int oi = u >> 1, st = u & 1;
        float s = 0.f;
        #pragma unroll
        for (int ww = 0; ww < 16; ww++) s += red[ww][oi][st];
        partials[(size_t)bi * 32 + oi * 2 + st] = s;
    }
}

// ---------------- K3c: stats + y2 -> LDS transpose -> BN+ReLU -> out ----------------
__global__ void __launch_bounds__(256, 8)
k3c(const uint16_t* __restrict__ y2, const float* __restrict__ partials,
    const float* __restrict__ gamma, const float* __restrict__ beta,
    float* __restrict__ out) {
    __shared__ uint16_t ty[16 * 256];   // [16 o][256 n] bf16, byte XOR bit4 by (o&7)
    __shared__ float stat[32];
    __shared__ float sbsh[32];
    int bi = blockIdx.x;                // 4096: b*256 + og*16 + nc
    int b = bi >> 8, og = (bi >> 4) & 15, nc = bi & 15;
    int u = threadIdx.x;
    const uint16_t* src = y2 + (((size_t)(b * 16 + og)) * N_ + nc * 256) * 16;
    u32x4 va = __builtin_nontemporal_load((const u32x4*)(src + (size_t)u * 16));
    u32x4 vb = __builtin_nontemporal_load((const u32x4*)(src + (size_t)u * 16 + 8));
    if (u < 32) {
        int oi = u >> 1, st = u & 1;
        float s = 0.f;
        #pragma unroll 4
        for (int t2 = 0; t2 < 32; t2++) {
            int row = (t2 >> 1) * 32 + og * 2 + (t2 & 1);
            s += partials[(size_t)row * 32 + oi * 2 + st];
        }
        stat[u] = s;
    }
    __syncthreads();
    if (u < 16) {
        float mean = stat[u * 2] / 65536.0f;
        float var  = stat[u * 2 + 1] / 65536.0f - mean * mean;
        int o_g = og * 16 + u;
        float scale = gamma[o_g] * rsqrtf(var + 1e-5f);
        sbsh[u * 2]     = scale;
        sbsh[u * 2 + 1] = beta[o_g] - mean * scale;
    }
    uint32_t words[8] = {va.x, va.y, va.z, va.w, vb.x, vb.y, vb.z, vb.w};
    #pragma unroll
    for (int h = 0; h < 8; h++) {
        int o0 = h * 2, o1 = h * 2 + 1;
        *(uint16_t*)((char*)ty + o0 * 512 + ((u * 2) ^ ((o0 & 7) << 4))) = (uint16_t)(words[h] & 0xffff);
        *(uint16_t*)((char*)ty + o1 * 512 + ((u * 2) ^ ((o1 & 7) << 4))) = (uint16_t)(words[h] >> 16);
    }
    __syncthreads();
    int o = u >> 4, k = u & 15;
    int x = (o & 7) << 4;
    int o_g = og * 16 + o;
    float scale = sbsh[o * 2], bias = sbsh[o * 2 + 1];
    float* dst = out + ((size_t)(b * OC_ + o_g)) * N_ + nc * 256;
    #pragma unroll
    for (int g2 = 0; g2 < 4; g2++) {
        uint64_t z = *(const uint64_t*)((const char*)ty + o * 512 + ((g2 * 128 + k * 8) ^ x));
        f32x4 r;
        r.x = fmaxf(0.f, fmaf(bf2f((uint32_t)(z       ) & 0xffff), scale, bias));
        r.y = fmaxf(0.f, fmaf(bf2f((uint32_t)(z >> 16 ) & 0xffff), scale, bias));
        r.z = fmaxf(0.f, fmaf(bf2f((uint32_t)(z >> 32 ) & 0xffff), scale, bias));
        r.w = fmaxf(0.f, fmaf(bf2f((uint32_t)(z >> 48 ) & 0xffff), scale, bias));
        __builtin_nontemporal_store(r, (f32x4*)(dst + g2 * 64 + k * 4));
    }
}

extern "C" void kernel_launch(void* const* d_in, const int* in_sizes, int n_in,
                              void* d_out, int out_size, void* d_ws, size_t ws_size,
                              hipStream_t stream) {
    const float* xyz1  = (const float*)d_in[0];
    const float* xyz2  = (const float*)d_in[1];
    const float* p1    = (const float*)d_in[2];
    const float* p2    = (const float*)d_in[3];
    const float* W     = (const float*)d_in[4];
    const float* gamma = (const float*)d_in[5];
    const float* beta  = (const float*)d_in[6];
    float* out = (float*)d_out;
    char* ws = (char*)d_ws;
    if (ws_size < (size_t)WS_NEED) return;

    int*      idxw     = (int*)(ws + IDXW_OFF);
    uint16_t* ztb      = (uint16_t*)(ws + ZTB_OFF);
    uint16_t* y1       = (uint16_t*)(ws + Y1_OFF);
    uint16_t* y2       = (uint16_t*)(ws + Y2_OFF);
    float*    partials = (float*)(ws + PART_OFF);
    uint16_t* w1b      = (uint16_t*)(ws + W1B_OFF);
    uint16_t* w2b      = (uint16_t*)(ws + W2B_OFF);

    hipLaunchKernelGGL(k0_prep, dim3(320),  dim3(256),  0, stream, W, w1b, w2b);
    hipLaunchKernelGGL(kA,      dim3(7168), dim3(256),  0, stream,
                       xyz1, xyz2, idxw, p1, p2, w1b, w2b, ztb, y1);
    hipLaunchKernelGGL(k3a,     dim3(512),  dim3(1024), 0, stream,
                       y1, ztb, idxw, y2, partials);
    hipLaunchKernelGGL(k3c,     dim3(4096), dim3(256),  0, stream,
                       y2, partials, gamma, beta, out);
}

// Round 21
// 89.916 us; speedup vs baseline: 1.1370x; 1.0420x over previous
//
#include <hip/hip_runtime.h>
#include <stdint.h>

// PointNet Feature Propagation, MI355X.  4 launches (best measured config = R14):
//  K0 : W f32 -> w1b bf16 [256][64], w2b bf16 [256][256]   (tiny)
//  A  : fused  k2_z = W2@p2 (0..1023, 32s x 128o)
//             + k1 three_nn (1024..3071, exact f32 INSERT, |s|^2 in pts.w)
//             + k2b y1=W1@p1 (3072..7167, 32n x 128o)
//  K3a: y2 = y1 + sum_k w_k * ztb[idx_k]  (LDS-staged gather) + BN partials
//  K3c: y2 -> LDS transpose -> (stats from partials) BN+ReLU -> d_out f32

#define B_   16
#define N_   4096
#define S_   1024
#define D1_  64
#define D2_  256
#define OC_  256

typedef __attribute__((ext_vector_type(8))) short bf16x8;
typedef __attribute__((ext_vector_type(4))) float f32x4;
typedef __attribute__((ext_vector_type(4))) unsigned int u32x4;
typedef __attribute__((ext_vector_type(2))) unsigned int u32x2;

// workspace layout (bytes)
#define IDXW_OFF 0u           // 2 MB
#define ZTB_OFF  2097152u     // 8 MB
#define Y1_OFF   10485760u    // 32 MB
#define Y2_OFF   44040192u    // 32 MB
#define PART_OFF 77594624u    // 64 KB
#define W1B_OFF  77662208u    // 32 KB
#define W2B_OFF  77694976u    // 128 KB
#define WS_NEED  77826048u

__device__ __forceinline__ uint16_t f2bf(float f) {
    union { float f; uint32_t u; } v; v.f = f;
    uint32_t r = v.u + 0x7FFFu + ((v.u >> 16) & 1u);   // RNE
    return (uint16_t)(r >> 16);
}
__device__ __forceinline__ float bf2f(uint32_t h) {
    union { uint32_t u; float f; } v; v.u = h << 16;
    return v.f;
}

#define INSERT(d, sidx, d0, d1, d2, i0, i1, i2) do {                      \
    bool ca = (d) < (d2); bool cb = (d) < (d1); bool cc = (d) < (d0);     \
    float _n1 = __builtin_amdgcn_fmed3f((d), (d0), (d1));                 \
    float _n2 = __builtin_amdgcn_fmed3f((d), (d1), (d2));                 \
    int _j2 = cb ? (i1) : (ca ? (sidx) : (i2));                          \
    int _j1 = cc ? (i0) : (cb ? (sidx) : (i1));                          \
    i0 = cc ? (sidx) : (i0);                                              \
    d0 = fminf((d), (d0)); d1 = _n1; d2 = _n2; i1 = _j1; i2 = _j2;        \
} while (0)

// ---------------- K0: weight conversion ----------------
__global__ void k0_prep(const float* __restrict__ W,
                        uint16_t* __restrict__ w1b, uint16_t* __restrict__ w2b) {
    int e = blockIdx.x * 256 + threadIdx.x;
    if (e >= OC_ * 320) return;
    int o = e / 320, c = e % 320;
    uint16_t b = f2bf(W[e]);
    if (c < 64) w1b[o * 64 + c] = b;
    else        w2b[o * 256 + (c - 64)] = b;
}

// ---------------- A: k2_z (0..1023) + k1 (1024..3071) + k2b (3072..7167) ----------------
__global__ void __launch_bounds__(256, 8)
kA(const float* __restrict__ xyz1, const float* __restrict__ xyz2,
   int* __restrict__ idxw, const float* __restrict__ p1,
   const float* __restrict__ p2, const uint16_t* __restrict__ w1b,
   const uint16_t* __restrict__ w2b, uint16_t* __restrict__ ztb,
   uint16_t* __restrict__ y1) {
    __shared__ char smem[16512];
    int i = blockIdx.x;
    int t = threadIdx.x, l = t & 63, w = t >> 6;
    if (i < 1024) {
        // ---- k2_z: ztb = W2@p2; 32s x 128o per block ----
        uint16_t* a_t = (uint16_t*)smem;   // [32 s][256 c] bf16, 512B rows, swz <<4
        int b = i >> 6, s0 = ((i >> 1) & 31) * 32, oh = i & 1;
        int sA = t & 31, cpg = t >> 5;
        const float* p2b = p2 + (size_t)b * D2_ * S_ + s0;
        #pragma unroll
        for (int j = 0; j < 16; j++) {
            int cp = cpg + 8 * j;
            float lo = p2b[(size_t)(2 * cp) * S_ + sA];
            float hi = p2b[(size_t)(2 * cp + 1) * S_ + sA];
            uint32_t pk = (uint32_t)f2bf(lo) | ((uint32_t)f2bf(hi) << 16);
            *(uint32_t*)((char*)a_t + sA * 512 + ((cp * 4) ^ ((sA & 7) << 4))) = pk;
        }
        __syncthreads();
        f32x4 acc[2][2] = {};   // [mi(s16)][oj(o16)]
        int ls = l & 15, swzs = (ls & 7) << 4;
        #pragma unroll
        for (int ks = 0; ks < 8; ks++) {
            int co = ks * 32 + (l >> 4) * 8;
            bf16x8 a0 = *(const bf16x8*)((const char*)a_t + ls * 512 + ((co * 2) ^ swzs));
            bf16x8 a1 = *(const bf16x8*)((const char*)a_t + (16 + ls) * 512 + ((co * 2) ^ swzs));
            bf16x8 bbf[2];
            #pragma unroll
            for (int oj = 0; oj < 2; oj++) {
                int o = oh * 128 + w * 32 + oj * 16 + ls;
                bbf[oj] = *(const bf16x8*)(w2b + (size_t)o * 256 + co);
            }
            #pragma unroll
            for (int oj = 0; oj < 2; oj++) {
                acc[0][oj] = __builtin_amdgcn_mfma_f32_16x16x32_bf16(a0, bbf[oj], acc[0][oj], 0, 0, 0);
                acc[1][oj] = __builtin_amdgcn_mfma_f32_16x16x32_bf16(a1, bbf[oj], acc[1][oj], 0, 0, 0);
            }
        }
        // direct fragment-native store: 16 lanes cover one 32B [s][16o] row
        #pragma unroll
        for (int mi = 0; mi < 2; mi++)
            #pragma unroll
            for (int oj = 0; oj < 2; oj++) {
                int og = oh * 8 + w * 2 + oj;
                uint16_t* zb = ztb + ((size_t)(b * 16 + og) * S_ + s0 + mi * 16 + (l >> 4) * 4) * 16 + ls;
                #pragma unroll
                for (int r = 0; r < 4; r++)
                    zb[(size_t)r * 16] = f2bf(acc[mi][oj][r]);
            }
    } else if (i < 3072) {
        // ---- k1: three_nn (|s|^2 in pts.w; 3-fma distance; shift-invariant order) ----
        int j1 = i - 1024;
        int b  = j1 >> 7;
        int n0 = (j1 & 127) * 32;
        float4* pts = (float4*)smem;    // [8 chunks][129]

        for (int s = t; s < S_; s += 256) {
            const float* p = xyz2 + ((size_t)b * S_ + s) * 3;
            float sx = p[0], sy = p[1], sz = p[2];
            float s2 = fmaf(sz, sz, fmaf(sy, sy, sx * sx));
            pts[(s >> 7) * 129 + (s & 127)] = make_float4(sx, sy, sz, s2);
        }
        __syncthreads();

        int chunk = t & 7, nidx = t >> 3;
        int n = n0 + nidx;
        const float* q = xyz1 + ((size_t)b * N_ + n) * 3;
        float ax = q[0], ay = q[1], az = q[2];
        float m2x = -2.0f * ax, m2y = -2.0f * ay, m2z = -2.0f * az;
        float q2 = fmaf(az, az, fmaf(ay, ay, ax * ax));

        float d0 = 3.4e38f, d1 = 3.4e38f, d2 = 3.4e38f;
        int   i0 = 0, i1 = 0, i2 = 0;

        const float4* base = pts + chunk * 129;
        int sbase = chunk * 128;
        #pragma unroll 4
        for (int j = 0; j < 128; j++) {
            float4 qq = base[j];
            int s = sbase + j;
            float d = fmaf(qq.x, m2x, fmaf(qq.y, m2y, fmaf(qq.z, m2z, qq.w)));
            INSERT(d, s, d0, d1, d2, i0, i1, i2);
        }
        #pragma unroll
        for (int m = 1; m <= 4; m <<= 1) {
            float e0 = __shfl_xor(d0, m), e1 = __shfl_xor(d1, m), e2 = __shfl_xor(d2, m);
            int   g0 = __shfl_xor(i0, m), g1 = __shfl_xor(i1, m), g2 = __shfl_xor(i2, m);
            INSERT(e0, g0, d0, d1, d2, i0, i1, i2);
            INSERT(e1, g1, d0, d1, d2, i0, i1, i2);
            INSERT(e2, g2, d0, d1, d2, i0, i1, i2);
        }
        if (chunk == 0) {
            float dd0 = d0 + q2, dd1 = d1 + q2, dd2 = d2 + q2;
            float r0 = 1.0f / (dd0 + 1e-8f), r1 = 1.0f / (dd1 + 1e-8f), r2 = 1.0f / (dd2 + 1e-8f);
            float rs = r0 + r1 + r2;
            float* fw = (float*)idxw;
            int bb = (b * N_ + n) * 8;
            idxw[bb + 0] = i0; idxw[bb + 1] = i1; idxw[bb + 2] = i2;
            fw[bb + 4] = r0 / rs; fw[bb + 5] = r1 / rs; fw[bb + 6] = r2 / rs;
        }
    } else {
        // ---- k2b: y1 = W1@p1; 32n x 128o per block ----
        int j2 = i - 3072;
        int b = j2 >> 8, n0 = ((j2 >> 1) & 127) * 32, oh = j2 & 1;
        uint16_t* pt = (uint16_t*)smem;   // [32 n][64 c], 128B rows, swz <<4
        {
            int nn = t & 31;
            const float* p1b = p1 + (size_t)b * D1_ * N_ + n0;
            #pragma unroll
            for (int j = 0; j < 4; j++) {
                int cp = (t >> 5) + 8 * j;
                float lo = p1b[(size_t)(2 * cp) * N_ + nn];
                float hi = p1b[(size_t)(2 * cp + 1) * N_ + nn];
                uint32_t pk = (uint32_t)f2bf(lo) | ((uint32_t)f2bf(hi) << 16);
                *(uint32_t*)((char*)pt + nn * 128 + ((cp * 4) ^ ((nn & 7) << 4))) = pk;
            }
        }
        bf16x8 af[2][2];
        #pragma unroll
        for (int ks = 0; ks < 2; ks++)
            #pragma unroll
            for (int mi = 0; mi < 2; mi++) {
                int o = oh * 128 + w * 32 + mi * 16 + (l & 15);
                af[ks][mi] = *(const bf16x8*)(w1b + (size_t)o * 64 + ks * 32 + (l >> 4) * 8);
            }
        f32x4 acc[2][2] = {};   // [mi(o)][bj(n)]
        __syncthreads();
        #pragma unroll
        for (int ks = 0; ks < 2; ks++) {
            bf16x8 bf[2];
            int co = ks * 32 + (l >> 4) * 8;
            #pragma unroll
            for (int bj = 0; bj < 2; bj++) {
                int nn = bj * 16 + (l & 15);
                bf[bj] = *(const bf16x8*)((const char*)pt + nn * 128 + ((co * 2) ^ ((nn & 7) << 4)));
            }
            #pragma unroll
            for (int mi = 0; mi < 2; mi++)
                #pragma unroll
                for (int bj = 0; bj < 2; bj++)
                    acc[mi][bj] = __builtin_amdgcn_mfma_f32_16x16x32_bf16(
                        af[ks][mi], bf[bj], acc[mi][bj], 0, 0, 0);
        }
        #pragma unroll
        for (int mi = 0; mi < 2; mi++) {
            int og = oh * 8 + w * 2 + mi;
            uint16_t* yb = y1 + ((size_t)(b * 16 + og)) * N_ * 16;
            #pragma unroll
            for (int bj = 0; bj < 2; bj++) {
                int n = n0 + bj * 16 + (l & 15);
                int oo = (l >> 4) * 4;
                u32x2 v;
                v.x = (uint32_t)f2bf(acc[mi][bj][0]) | ((uint32_t)f2bf(acc[mi][bj][1]) << 16);
                v.y = (uint32_t)f2bf(acc[mi][bj][2]) | ((uint32_t)f2bf(acc[mi][bj][3]) << 16);
                __builtin_nontemporal_store(v, (u32x2*)(yb + (size_t)n * 16 + oo));
            }
        }
    }
}

// ---------------- K3a: LDS-staged gather -> y2 bf16 + BN partials ----------------
__global__ void __launch_bounds__(1024, 8)
k3a(const uint16_t* __restrict__ y1, const uint16_t* __restrict__ ztb,
    const int* __restrict__ idxw, uint16_t* __restrict__ y2,
    float* __restrict__ partials) {
    __shared__ char zsm[49152];          // [1024 s][48B] rows (32B used)
    __shared__ float red[16][16][2];
    int bi = blockIdx.x;                 // 512: b*32 + og*2 + nh
    int b = bi >> 5, og = (bi >> 1) & 15, nh = bi & 1;
    int u = threadIdx.x, l = u & 63, w = u >> 6;   // 16 waves
    {
        const u32x4* src = (const u32x4*)(ztb + ((size_t)(b * 16 + og)) * S_ * 16);
        #pragma unroll
        for (int k = 0; k < 2; k++) {
            int g = k * 1024 + u;
            u32x4 v = src[g];
            *(u32x4*)(zsm + (g >> 1) * 48 + (g & 1) * 16) = v;
        }
    }
    __syncthreads();
    int q = l >> 2, sub = l & 3;
    float s1l[4] = {0.f, 0.f, 0.f, 0.f}, s2l[4] = {0.f, 0.f, 0.f, 0.f};
    int nbase = nh * 2048 + w * 128;
    const uint16_t* y1b = y1 + ((size_t)(b * 16 + og)) * N_ * 16;
    uint16_t* y2b = y2 + ((size_t)(b * 16 + og)) * N_ * 16;
    #pragma unroll 2
    for (int it = 0; it < 8; it++) {
        int n = nbase + it * 16 + q;
        u32x2 y1v = __builtin_nontemporal_load((const u32x2*)(y1b + (size_t)n * 16 + sub * 4));
        const int* ib = idxw + ((size_t)(b * N_ + n)) * 8;
        int4   iv = *(const int4*)ib;
        float4 wv = *((const float4*)ib + 1);
        u32x2 z0 = *(const u32x2*)(zsm + iv.x * 48 + sub * 8);
        u32x2 z1 = *(const u32x2*)(zsm + iv.y * 48 + sub * 8);
        u32x2 z2 = *(const u32x2*)(zsm + iv.z * 48 + sub * 8);
        float a0 = bf2f(y1v.x & 0xffff) + wv.x * bf2f(z0.x & 0xffff) + wv.y * bf2f(z1.x & 0xffff) + wv.z * bf2f(z2.x & 0xffff);
        float a1 = bf2f(y1v.x >> 16)    + wv.x * bf2f(z0.x >> 16)    + wv.y * bf2f(z1.x >> 16)    + wv.z * bf2f(z2.x >> 16);
        float a2 = bf2f(y1v.y & 0xffff) + wv.x * bf2f(z0.y & 0xffff) + wv.y * bf2f(z1.y & 0xffff) + wv.z * bf2f(z2.y & 0xffff);
        float a3 = bf2f(y1v.y >> 16)    + wv.x * bf2f(z0.y >> 16)    + wv.y * bf2f(z1.y >> 16)    + wv.z * bf2f(z2.y >> 16);
        s1l[0] += a0; s2l[0] += a0 * a0;
        s1l[1] += a1; s2l[1] += a1 * a1;
        s1l[2] += a2; s2l[2] += a2 * a2;
        s1l[3] += a3; s2l[3] += a3 * a3;
        u32x2 vv;
        vv.x = (uint32_t)f2bf(a0) | ((uint32_t)f2bf(a1) << 16);
        vv.y = (uint32_t)f2bf(a2) | ((uint32_t)f2bf(a3) << 16);
        __builtin_nontemporal_store(vv, (u32x2*)(y2b + (size_t)n * 16 + sub * 4));
    }
    #pragma unroll
    for (int m = 4; m <= 32; m <<= 1)
        #pragma unroll
        for (int j = 0; j < 4; j++) {
            s1l[j] += __shfl_xor(s1l[j], m);
            s2l[j] += __shfl_xor(s2l[j], m);
        }
    if (l < 4) {
        #pragma unroll
        for (int j = 0; j < 4; j++) {
            red[w][sub * 4 + j][0] = s1l[j];
            red[w][sub * 4 + j][1] = s2l[j];
        }
    }
    __syncthreads();
    if (u < 32) {
        int oi = u >> 1, st = u & 1;
        float s = 0.f;
        #pragma unroll
        for (int ww = 0; ww < 16; ww++) s += red[ww][oi][st];
        partials[(size_t)bi * 32 + oi * 2 + st] = s;
    }
}

// ---------------- K3c: stats + y2 -> LDS transpose -> BN+ReLU -> out ----------------
__global__ void __launch_bounds__(256, 8)
k3c(const uint16_t* __restrict__ y2, const float* __restrict__ partials,
    const float* __restrict__ gamma, const float* __restrict__ beta,
    float* __restrict__ out) {
    __shared__ uint16_t ty[16 * 256];   // [16 o][256 n] bf16, byte XOR bit4 by (o&7)
    __shared__ float stat[32];
    __shared__ float sbsh[32];
    int bi = blockIdx.x;                // 4096: b*256 + og*16 + nc
    int b = bi >> 8, og = (bi >> 4) & 15, nc = bi & 15;
    int u = threadIdx.x;
    const uint16_t* src = y2 + (((size_t)(b * 16 + og)) * N_ + nc * 256) * 16;
    u32x4 va = __builtin_nontemporal_load((const u32x4*)(src + (size_t)u * 16));
    u32x4 vb = __builtin_nontemporal_load((const u32x4*)(src + (size_t)u * 16 + 8));
    if (u < 32) {
        int oi = u >> 1, st = u & 1;
        float s = 0.f;
        #pragma unroll 4
        for (int t2 = 0; t2 < 32; t2++) {
            int row = (t2 >> 1) * 32 + og * 2 + (t2 & 1);
            s += partials[(size_t)row * 32 + oi * 2 + st];
        }
        stat[u] = s;
    }
    __syncthreads();
    if (u < 16) {
        float mean = stat[u * 2] / 65536.0f;
        float var  = stat[u * 2 + 1] / 65536.0f - mean * mean;
        int o_g = og * 16 + u;
        float scale = gamma[o_g] * rsqrtf(var + 1e-5f);
        sbsh[u * 2]     = scale;
        sbsh[u * 2 + 1] = beta[o_g] - mean * scale;
    }
    uint32_t words[8] = {va.x, va.y, va.z, va.w, vb.x, vb.y, vb.z, vb.w};
    #pragma unroll
    for (int h = 0; h < 8; h++) {
        int o0 = h * 2, o1 = h * 2 + 1;
        *(uint16_t*)((char*)ty + o0 * 512 + ((u * 2) ^ ((o0 & 7) << 4))) = (uint16_t)(words[h] & 0xffff);
        *(uint16_t*)((char*)ty + o1 * 512 + ((u * 2) ^ ((o1 & 7) << 4))) = (uint16_t)(words[h] >> 16);
    }
    __syncthreads();
    int o = u >> 4, k = u & 15;
    int x = (o & 7) << 4;
    int o_g = og * 16 + o;
    float scale = sbsh[o * 2], bias = sbsh[o * 2 + 1];
    float* dst = out + ((size_t)(b * OC_ + o_g)) * N_ + nc * 256;
    #pragma unroll
    for (int g2 = 0; g2 < 4; g2++) {
        uint64_t z = *(const uint64_t*)((const char*)ty + o * 512 + ((g2 * 128 + k * 8) ^ x));
        f32x4 r;
        r.x = fmaxf(0.f, fmaf(bf2f((uint32_t)(z       ) & 0xffff), scale, bias));
        r.y = fmaxf(0.f, fmaf(bf2f((uint32_t)(z >> 16 ) & 0xffff), scale, bias));
        r.z = fmaxf(0.f, fmaf(bf2f((uint32_t)(z >> 32 ) & 0xffff), scale, bias));
        r.w = fmaxf(0.f, fmaf(bf2f((uint32_t)(z >> 48 ) & 0xffff), scale, bias));
        __builtin_nontemporal_store(r, (f32x4*)(dst + g2 * 64 + k * 4));
    }
}

extern "C" void kernel_launch(void* const* d_in, const int* in_sizes, int n_in,
                              void* d_out, int out_size, void* d_ws, size_t ws_size,
                              hipStream_t stream) {
    const float* xyz1  = (const float*)d_in[0];
    const float* xyz2  = (const float*)d_in[1];
    const float* p1    = (const float*)d_in[2];
    const float* p2    = (const float*)d_in[3];
    const float* W     = (const float*)d_in[4];
    const float* gamma = (const float*)d_in[5];
    const float* beta  = (const float*)d_in[6];
    float* out = (float*)d_out;
    char* ws = (char*)d_ws;
    if (ws_size < (size_t)WS_NEED) return;

    int*      idxw     = (int*)(ws + IDXW_OFF);
    uint16_t* ztb      = (uint16_t*)(ws + ZTB_OFF);
    uint16_t* y1       = (uint16_t*)(ws + Y1_OFF);
    uint16_t* y2       = (uint16_t*)(ws + Y2_OFF);
    float*    partials = (float*)(ws + PART_OFF);
    uint16_t* w1b      = (uint16_t*)(ws + W1B_OFF);
    uint16_t* w2b      = (uint16_t*)(ws + W2B_OFF);

    hipLaunchKernelGGL(k0_prep, dim3(320),  dim3(256),  0, stream, W, w1b, w2b);
    hipLaunchKernelGGL(kA,      dim3(7168), dim3(256),  0, stream,
                       xyz1, xyz2, idxw, p1, p2, w1b, w2b, ztb, y1);
    hipLaunchKernelGGL(k3a,     dim3(512),  dim3(1024), 0, stream,
                       y1, ztb, idxw, y2, partials);
    hipLaunchKernelGGL(k3c,     dim3(4096), dim3(256),  0, stream,
                       y2, partials, gamma, beta, out);
}